// Round 11
// baseline (1698.445 us; speedup 1.0000x reference)
//
#include <hip/hip_runtime.h>
#include <stdint.h>
#include <limits.h>

#define BB 64
#define HH 512
#define WW 512
#define WPR 8                  // 64-bit words per row
#define HWP (HH*WW)            // 262144
#define NPIX (BB*HWP)          // 16777216
#define NROWS (BB*HH)          // 32768
#define RS 128                 // exact max runs/row in opened mask (len>=3, gap>=1)
#define MAXRUNS (NROWS*RS)     // 4194304
#define KPR 32                 // flatten threads per row (hash capacity bound)
#define MAXROOTS 32768         // per-image root-candidate cap (min component = 9 px)

typedef unsigned char u8;
typedef unsigned long long u64;

__device__ __forceinline__ int imax(int a, int b){ return a > b ? a : b; }

// ---------------- threshold + bit-pack, 16 px/thread (full occupancy) -----
__global__ void k_threshpack(const float* __restrict__ x, u64* __restrict__ bits,
                             int* __restrict__ rootcnt){
  int t = blockIdx.x*blockDim.x + threadIdx.x;      // 0 .. NPIX/16
  if (t < BB) rootcnt[t] = 0;
  const float4* X = reinterpret_cast<const float4*>(x) + (size_t)t*4;
  unsigned m = 0;
  #pragma unroll
  for (int q = 0; q < 4; ++q){
    float4 v = X[q];
    m |= (unsigned)(v.x > -0.5f) << (q*4 + 0);
    m |= (unsigned)(v.y > -0.5f) << (q*4 + 1);
    m |= (unsigned)(v.z > -0.5f) << (q*4 + 2);
    m |= (unsigned)(v.w > -0.5f) << (q*4 + 3);
  }
  int sub = t & 3;
  unsigned p1 = __shfl_xor(m, 1);
  unsigned v32 = (sub & 1) ? (p1 | (m << 16)) : (m | (p1 << 16));
  unsigned p2 = __shfl_xor(v32, 2);
  if ((sub & 3) == 0){
    u64 w = (u64)v32 | ((u64)p2 << 32);
    bits[t >> 2] = w;
  }
}

// ---------------- helpers for bit morphology ----------------
__device__ __forceinline__ u64 hshift3_and(u64 c, u64 l, u64 r){
  return c & ((c << 1) | (l >> 63)) & ((c >> 1) | (r << 63));
}
__device__ __forceinline__ u64 hshift3_or(u64 c, u64 l, u64 r){
  return c | (c << 1) | (l >> 63) | (c >> 1) | (r << 63);
}
__device__ __forceinline__ u64 hshift5_and(u64 c, u64 l, u64 r){
  return hshift3_and(c, l, r) & ((c << 2) | (l >> 62)) & ((c >> 2) | (r << 62));
}
__device__ __forceinline__ u64 hshift5_or(u64 c, u64 l, u64 r){
  return hshift3_or(c, l, r) | (c << 2) | (l >> 62) | (c >> 2) | (r << 62);
}

// load word (row, wi) with image-vertical zero pad
__device__ __forceinline__ u64 ldw(const u64* __restrict__ in, int img, int rowInImg, int wi){
  if ((unsigned)rowInImg >= (unsigned)HH) return 0ULL;
  if ((unsigned)wi >= (unsigned)WPR) return 0ULL;
  return in[((size_t)img*HH + rowInImg)*WPR + wi];
}

// ---------------- LDS union-find (slab-local, path halving) ---------------
__device__ __forceinline__ int lfind(int* lp, int p){
  while (true){
    int q = lp[p];
    int g = lp[q];
    if (q == g) return q;
    atomicMin(&lp[p], g);
    p = g;
  }
}
__device__ __forceinline__ void lunion(int* lp, int a, int b){
  while (true){
    a = lfind(lp, a);
    b = lfind(lp, b);
    if (a == b) return;
    if (a < b){ int t = a; a = b; b = t; }
    int old = atomicMin(&lp[a], b);
    if (old == a) return;
    a = old;
  }
}

// ---------------- open (erode3+dilate3) + runs + SLAB-LOCAL union-find ----
#define ORPB 32
__global__ __launch_bounds__(256)
void k_openlocal(const u64* __restrict__ bits, uint32_t* __restrict__ runs,
                 int* __restrict__ cnt, int* __restrict__ parent,
                 int* __restrict__ area, int* __restrict__ clabel){
  __shared__ u64 er[ORPB + 2][WPR];
  __shared__ u64 dl[ORPB][WPR];
  __shared__ uint32_t lruns[ORPB][RS];
  __shared__ int lcnt[ORPB];
  __shared__ int lparent[ORPB*RS];     // 4096 entries
  int R0 = blockIdx.x * ORPB;
  int img = R0 >> 9;
  int y0 = R0 & (HH - 1);

  // phase E: erode3x3 rows y0-1 .. y0+32 (reads bitmap from L2)
  for (int s = threadIdx.x; s < (ORPB + 2)*WPR; s += 256){
    int j = s >> 3;                           // er row; image row y0-1+j
    int wi = s & 7;
    int yy = y0 - 1 + j;
    u64 acc = ~0ULL;
    #pragma unroll
    for (int dy = -1; dy <= 1; ++dy){
      int y = yy + dy;
      u64 c = ldw(bits, img, y, wi);
      u64 l = ldw(bits, img, y, wi - 1);
      u64 r = ldw(bits, img, y, wi + 1);
      acc &= ((unsigned)y < (unsigned)HH) ? hshift3_and(c, l, r) : 0ULL;
    }
    if ((unsigned)yy >= (unsigned)HH) acc = 0ULL;
    er[j][wi] = acc;
  }
  __syncthreads();

  // phase D: dilate3x3 -> dl
  for (int s = threadIdx.x; s < ORPB*WPR; s += 256){
    int ri = s >> 3;
    int wi = s & 7;
    u64 acc = 0ULL;
    #pragma unroll
    for (int dy = 0; dy < 3; ++dy){
      int li = ri + dy;
      u64 c = er[li][wi];
      u64 l = (wi > 0) ? er[li][wi-1] : 0ULL;
      u64 r = (wi < 7) ? er[li][wi+1] : 0ULL;
      acc |= hshift3_or(c, l, r);
    }
    dl[ri][wi] = acc;
  }
  __syncthreads();

  // init local parent (identity)
  for (int i = threadIdx.x; i < ORPB*RS; i += 256) lparent[i] = i;

  // phase R: run extraction, one thread per row (writes global + LDS copies)
  if (threadIdx.x < ORPB){
    int ri = threadIdx.x;
    int r = R0 + ri;
    u64 w[8];
    #pragma unroll
    for (int i = 0; i < 8; ++i) w[i] = dl[ri][i];
    int base = r*RS;
    int k = 0;
    int pending = -1;
    u64 carry = 0;
    #pragma unroll
    for (int wi = 0; wi < 8; ++wi){
      u64 b = w[wi];
      u64 nb0 = (wi < 7) ? (w[wi+1] & 1ULL) : 0ULL;
      u64 starts = b & ~((b << 1) | carry);
      u64 ends   = b & ~(b >> 1);
      if (nb0) ends &= ~(1ULL << 63);
      carry = b >> 63;
      while (ends){
        int e = __ffsll((long long)ends) - 1; ends &= ends - 1;
        int s;
        if (pending >= 0){ s = pending; pending = -1; }
        else { s = wi*64 + (__ffsll((long long)starts) - 1); starts &= starts - 1; }
        uint32_t rv = (uint32_t)s | ((uint32_t)(wi*64 + e) << 16);
        int id = base + k;
        runs[id] = rv; lruns[ri][k] = rv;
        area[id] = 0; clabel[id] = 0;
        k++;
      }
      if (starts) pending = wi*64 + (__ffsll((long long)starts) - 1);
    }
    cnt[r] = k; lcnt[ri] = k;
  }
  __syncthreads();

  // phase L: local link rows 1..31 (8 threads per row = 256 threads exactly)
  {
    int ri = threadIdx.x >> 3;
    int k0 = threadIdx.x & 7;
    if (ri > 0){
      int ca = lcnt[ri], cb = lcnt[ri-1];
      if (cb > 0){
        for (int k = k0; k < ca; k += 8){
          uint32_t ra = lruns[ri][k]; int sA = (int)(ra & 0xffff), eA = (int)(ra >> 16);
          int lo = 0, hi = cb, target = sA - 1;
          while (lo < hi){
            int mid = (lo + hi) >> 1;
            if ((int)(lruns[ri-1][mid] >> 16) < target) lo = mid + 1; else hi = mid;
          }
          for (int j = lo; j < cb; ++j){
            if ((int)(lruns[ri-1][j] & 0xffff) > eA + 1) break;
            lunion(lparent, ri*RS + k, (ri-1)*RS + j);
          }
        }
      }
    }
  }
  __syncthreads();

  // phase W: write global parent = slab root (global id space)
  {
    int ri = threadIdx.x >> 3;
    int k0 = threadIdx.x & 7;
    int n = lcnt[ri];
    for (int k = k0; k < n; k += 8){
      int lid = ri*RS + k;
      parent[R0*RS + lid] = R0*RS + lfind(lparent, lid);
    }
  }
}

// ---------------- global union-find (path halving) ----------------
__device__ __forceinline__ int uf_find(int* parent, int p){
  while (true){
    int q = parent[p];
    int g = parent[q];
    if (q == g) return q;
    atomicMin(&parent[p], g);
    p = g;
  }
}
__device__ __forceinline__ void uf_union(int* parent, int a, int b){
  while (true){
    a = uf_find(parent, a);
    b = uf_find(parent, b);
    if (a == b) return;
    if (a < b){ int t = a; a = b; b = t; }
    int old = atomicMin(&parent[a], b);
    if (old == a) return;
    a = old;
  }
}

// ---------------- boundary link: only rows at slab seams ------------------
#define NBND (HH/ORPB - 1)
__global__ void k_linkb(const uint32_t* __restrict__ runs, const int* __restrict__ cnt,
                        int* __restrict__ parent){
  int t = blockIdx.x*blockDim.x + threadIdx.x;
  int bi = t >> 3, k0 = t & 7;
  if (bi >= BB*NBND) return;
  int img = bi / NBND, j = bi % NBND;
  int r = img*HH + (j + 1)*ORPB;              // top row of slab; link to r-1
  int ca = cnt[r];
  int cb = cnt[r-1];
  if (cb == 0) return;
  const uint32_t* RB = runs + (size_t)(r-1)*RS;
  for (int k = k0; k < ca; k += 8){
    int id = r*RS + k;
    uint32_t ra = runs[id]; int sA = (int)(ra & 0xffff), eA = (int)(ra >> 16);
    int lo = 0, hi = cb, target = sA - 1;
    while (lo < hi){
      int mid = (lo + hi) >> 1;
      if ((int)(RB[mid] >> 16) < target) lo = mid + 1; else hi = mid;
    }
    for (int jj = lo; jj < cb; ++jj){
      uint32_t rb = RB[jj];
      if ((int)(rb & 0xffff) > eA + 1) break;
      uf_union(parent, id, (r-1)*RS + jj);
    }
  }
}

// ---------------- flatten: find + hash-accumulate + ROOT COMPACTION -------
// Each root slot (parent[id]==id) is visited exactly once grid-wide ->
// append its id to the per-image candidate list here (free compaction).
#define FHASH 1024
__global__ __launch_bounds__(256)
void k_flatten(const uint32_t* __restrict__ runs, const int* __restrict__ cnt,
               int* __restrict__ parent, int* __restrict__ area,
               int* __restrict__ clabel, int* __restrict__ rootcnt,
               int* __restrict__ rootI){
  __shared__ int hKey[FHASH];
  __shared__ int hSum[FHASH];
  __shared__ int hMax[FHASH];
  for (int i = threadIdx.x; i < FHASH; i += 256){ hKey[i] = -1; hSum[i] = 0; hMax[i] = 0; }
  __syncthreads();
  int t = blockIdx.x*blockDim.x + threadIdx.x;
  int r = t / KPR, k0 = t % KPR;
  int n = cnt[r];
  int y = r & (HH - 1);
  int img = r >> 9;
  for (int k = k0; k < n; k += KPR){
    int id = r*RS + k;
    int p = parent[id];
    while (true){ int q = parent[p]; if (q == p) break; p = q; }   // read-only find
    parent[id] = p;                     // final flatten (true root; forest static)
    if (p == id){                       // root slot: compact (exactly once grid-wide)
      int idx = atomicAdd(&rootcnt[img], 1);
      if (idx < MAXROOTS) rootI[img*MAXROOTS + idx] = id;
    }
    uint32_t run = runs[id]; int s = (int)(run & 0xffff), e = (int)(run >> 16);
    int len = e - s + 1, lab = y*WW + e + 1;
    unsigned h = ((unsigned)p * 2654435761u) & (FHASH - 1);
    while (true){
      int cur = hKey[h];
      if (cur == p) break;
      if (cur == -1){
        int old = atomicCAS(&hKey[h], -1, p);
        if (old == -1 || old == p) break;
      }
      h = (h + 1) & (FHASH - 1);
    }
    atomicAdd(&hSum[h], len);
    atomicMax(&hMax[h], lab);
  }
  __syncthreads();
  for (int i = threadIdx.x; i < FHASH; i += 256){
    int key = hKey[i];
    if (key >= 0){
      atomicAdd(&area[key], hSum[i]);
      atomicMax(&clabel[key], hMax[i]);
    }
  }
}

// ---------------- top-2 per image over compacted candidates ---------------
__device__ __forceinline__ void ins2(int v, int i, int& v1, int& i1, int& v2, int& i2){
  if (v > v1 || (v == v1 && i < i1)) { v2 = v1; i2 = i1; v1 = v; i1 = i; }
  else if (v > v2 || (v == v2 && i < i2)) { v2 = v; i2 = i; }
}

__global__ __launch_bounds__(256)
void k_top2(const int* __restrict__ rootcnt, const int* __restrict__ rootI,
            const int* __restrict__ area, const int* __restrict__ clabel,
            int* __restrict__ keepL){
  __shared__ int sv1[256], si1[256], sv2[256], si2[256];
  int b = blockIdx.x;
  int n = rootcnt[b]; if (n > MAXROOTS) n = MAXROOTS;
  int v1 = 0, i1 = INT_MAX, v2 = 0, i2 = INT_MAX;
  for (int k = threadIdx.x; k < n; k += 256){
    int id = rootI[b*MAXROOTS + k];
    int a = area[id];
    if (a < 200) continue;                 // MIN_AREA
    ins2(a, clabel[id], v1, i1, v2, i2);
  }
  int t = threadIdx.x;
  sv1[t] = v1; si1[t] = i1; sv2[t] = v2; si2[t] = i2;
  __syncthreads();
  for (int s = 128; s > 0; s >>= 1){
    if (t < s){
      int a1 = sv1[t], b1 = si1[t], a2 = sv2[t], b2 = si2[t];
      ins2(sv1[t+s], si1[t+s], a1, b1, a2, b2);
      ins2(sv2[t+s], si2[t+s], a1, b1, a2, b2);
      sv1[t] = a1; si1[t] = b1; sv2[t] = a2; si2[t] = b2;
    }
    __syncthreads();
  }
  if (t == 0){
    keepL[b*2 + 0] = (sv1[0] > 0) ? si1[0] : 0;   // 0 invalid (labels >= 1)
    keepL[b*2 + 1] = (sv2[0] > 0) ? si2[0] : 0;
  }
}

// ---------------- fused keep-build + close (dilate5+erode5) + expand ------
__device__ __forceinline__ u64 rmask(int s, int e){  // bits s..e inclusive
  u64 hi = (e >= 63) ? ~0ULL : ((1ULL << (e + 1)) - 1);
  u64 lo = (1ULL << s) - 1;
  return hi & ~lo;
}

#define CRPB 32
__global__ __launch_bounds__(256)
void k_closeexpand(const uint32_t* __restrict__ runs, const int* __restrict__ cnt,
                   const int* __restrict__ parent, const int* __restrict__ clabel,
                   const int* __restrict__ keepL, float* __restrict__ out){
  __shared__ u64 kp[CRPB + 8][WPR];   // keep rows y0-4 .. y0+35
  __shared__ u64 dil[CRPB + 4][WPR];  // dilated rows y0-2 .. y0+33
  __shared__ u64 ero[CRPB][WPR];
  int R0 = blockIdx.x * CRPB;
  int img = R0 >> 9;
  int y0 = R0 & (HH - 1);
  int L1 = keepL[img*2], L2 = keepL[img*2 + 1];
  // phase 0: build keep bit rows from kept runs (thread per row, 40 rows)
  for (int s = threadIdx.x; s < CRPB + 8; s += 256){
    int y = y0 + s - 4;
    u64 wb[8] = {0,0,0,0,0,0,0,0};
    if ((unsigned)y < (unsigned)HH){
      int row = img*HH + y;
      int n = cnt[row];
      for (int k = 0; k < n; ++k){
        int id = row*RS + k;
        int L = clabel[parent[id]];           // parent flattened -> 1 hop
        if (L != L1 && L != L2) continue;
        uint32_t run = runs[id]; int st = (int)(run & 0xffff), e = (int)(run >> 16);
        int w0 = st >> 6, w1 = e >> 6;
        if (w0 == w1) wb[w0] |= rmask(st & 63, e & 63);
        else {
          wb[w0] |= rmask(st & 63, 63);
          for (int wi = w0 + 1; wi < w1; ++wi) wb[wi] = ~0ULL;
          wb[w1] |= rmask(0, e & 63);
        }
      }
    }
    #pragma unroll
    for (int wi = 0; wi < 8; ++wi) kp[s][wi] = wb[wi];
  }
  __syncthreads();
  // phase 1: dilate5 rows y0-2 .. y0+33
  for (int s = threadIdx.x; s < (CRPB + 4)*WPR; s += 256){
    int li = s >> 3;                           // kp index li+2 is center
    int wi = s & 7;
    u64 acc = 0ULL;
    #pragma unroll
    for (int dy = -2; dy <= 2; ++dy){
      int ki = li + 2 + dy;                    // 0..39
      u64 c = kp[ki][wi];
      u64 l = (wi > 0) ? kp[ki][wi-1] : 0ULL;
      u64 r = (wi < 7) ? kp[ki][wi+1] : 0ULL;
      acc |= hshift5_or(c, l, r);
    }
    dil[li][wi] = acc;
  }
  __syncthreads();
  // phase 2: erode5 center rows (zero pad outside image)
  for (int s = threadIdx.x; s < CRPB*WPR; s += 256){
    int ri = s >> 3;
    int wi = s & 7;
    int y = y0 + ri;
    u64 acc = ~0ULL;
    #pragma unroll
    for (int dy = -2; dy <= 2; ++dy){
      int yy = y + dy;
      u64 h;
      if ((unsigned)yy >= (unsigned)HH) h = 0ULL;
      else {
        int li = ri + 2 + dy;
        u64 c = dil[li][wi];
        u64 l = (wi > 0) ? dil[li][wi-1] : 0ULL;
        u64 r = (wi < 7) ? dil[li][wi+1] : 0ULL;
        h = hshift5_and(c, l, r);
      }
      acc &= h;
    }
    ero[ri][wi] = acc;
  }
  __syncthreads();
  // phase 3: expand to f32, coalesced float4 stores
  float4* O = reinterpret_cast<float4*>(out + (size_t)R0*WW);
  for (int i = threadIdx.x; i < CRPB*WW/4; i += 256){
    int px = i * 4;
    int row = px >> 9;
    int x = px & (WW - 1);
    u64 word = ero[row][x >> 6];
    unsigned nib = (unsigned)((word >> (x & 63)) & 0xFULL);
    float4 f;
    f.x = (float)( nib       & 1);
    f.y = (float)((nib >> 1) & 1);
    f.z = (float)((nib >> 2) & 1);
    f.w = (float)((nib >> 3) & 1);
    O[i] = f;
  }
}

// ---------------- launch ----------------
extern "C" void kernel_launch(void* const* d_in, const int* in_sizes, int n_in,
                              void* d_out, int out_size, void* d_ws, size_t ws_size,
                              hipStream_t stream){
  const float* x = (const float*)d_in[0];
  float* out = (float*)d_out;
  char* ws = (char*)d_ws;

  const size_t BITS_OFF    = 0;                         // 2 MiB (thresh bitmap)
  const size_t RUNS_OFF    = BITS_OFF   + 2097152ull;   // 16 MiB
  const size_t PAR_OFF     = RUNS_OFF   + (size_t)MAXRUNS*4;
  const size_t AREA_OFF    = PAR_OFF    + (size_t)MAXRUNS*4;
  const size_t CLAB_OFF    = AREA_OFF   + (size_t)MAXRUNS*4;
  const size_t CNT_OFF     = CLAB_OFF   + (size_t)MAXRUNS*4;
  const size_t RCNT_OFF    = CNT_OFF    + (size_t)NROWS*4;
  const size_t RI_OFF      = RCNT_OFF   + 1024ull;      // 8 MiB
  const size_t KEEPL_OFF   = RI_OFF     + (size_t)BB*MAXROOTS*4;

  u64*      bits     = (u64*)(ws + BITS_OFF);
  uint32_t* runs     = (uint32_t*)(ws + RUNS_OFF);
  int*      parent   = (int*)(ws + PAR_OFF);
  int*      area     = (int*)(ws + AREA_OFF);
  int*      clabel   = (int*)(ws + CLAB_OFF);
  int*      cnt      = (int*)(ws + CNT_OFF);
  int*      rootcnt  = (int*)(ws + RCNT_OFF);
  int*      rootI    = (int*)(ws + RI_OFF);
  int*      keepL    = (int*)(ws + KEEPL_OFF);

  const int T = 256;
  dim3 blk(T);

  // 1) threshold+pack (full occupancy stream read; zeroes rootcnt)
  k_threshpack<<<dim3(NPIX/16/T), blk, 0, stream>>>(x, bits, rootcnt);
  // 2) open + runs + slab-local union-find (LDS)
  k_openlocal<<<dim3(NROWS/ORPB), blk, 0, stream>>>(bits, runs, cnt, parent, area, clabel);
  // 3) boundary link (960 rows only)
  k_linkb<<<dim3((BB*NBND*8 + T - 1)/T), blk, 0, stream>>>(runs, cnt, parent);
  // 4) flatten + block-hash accumulate + root compaction
  k_flatten<<<dim3(NROWS*KPR/T), blk, 0, stream>>>(runs, cnt, parent, area, clabel,
                                                   rootcnt, rootI);
  // 5) top-2 per image over compacted candidates
  k_top2<<<dim3(BB), blk, 0, stream>>>(rootcnt, rootI, area, clabel, keepL);
  // 6) fused keep-build + close + expand -> f32 out
  k_closeexpand<<<dim3(NROWS/CRPB), blk, 0, stream>>>(runs, cnt, parent, clabel, keepL, out);

  (void)in_sizes; (void)n_in; (void)out_size; (void)ws_size;
}

// Round 12
// 119.828 us; speedup vs baseline: 14.1741x; 14.1741x over previous
//
#include <hip/hip_runtime.h>
#include <stdint.h>
#include <limits.h>

#define BB 64
#define HH 512
#define WW 512
#define WPR 8                  // 64-bit words per row
#define HWP (HH*WW)            // 262144
#define NPIX (BB*HWP)          // 16777216
#define NROWS (BB*HH)          // 32768
#define RS 128                 // exact max runs/row in opened mask (len>=3, gap>=1)
#define MAXRUNS (NROWS*RS)     // 4194304
#define KPR 32                 // flatten/roots threads per row (hash capacity bound)
#define MAXROOTS 2048          // area>=200 roots per image <= 262144/200 = 1310

typedef unsigned char u8;
typedef unsigned long long u64;

__device__ __forceinline__ int imax(int a, int b){ return a > b ? a : b; }

// ---------------- threshold + bit-pack, 16 px/thread (full occupancy) -----
__global__ void k_threshpack(const float* __restrict__ x, u64* __restrict__ bits,
                             int* __restrict__ rootcnt){
  int t = blockIdx.x*blockDim.x + threadIdx.x;      // 0 .. NPIX/16
  if (t < BB) rootcnt[t] = 0;
  const float4* X = reinterpret_cast<const float4*>(x) + (size_t)t*4;
  unsigned m = 0;
  #pragma unroll
  for (int q = 0; q < 4; ++q){
    float4 v = X[q];
    m |= (unsigned)(v.x > -0.5f) << (q*4 + 0);
    m |= (unsigned)(v.y > -0.5f) << (q*4 + 1);
    m |= (unsigned)(v.z > -0.5f) << (q*4 + 2);
    m |= (unsigned)(v.w > -0.5f) << (q*4 + 3);
  }
  int sub = t & 3;
  unsigned p1 = __shfl_xor(m, 1);
  unsigned v32 = (sub & 1) ? (p1 | (m << 16)) : (m | (p1 << 16));
  unsigned p2 = __shfl_xor(v32, 2);
  if ((sub & 3) == 0){
    u64 w = (u64)v32 | ((u64)p2 << 32);
    bits[t >> 2] = w;
  }
}

// ---------------- helpers for bit morphology ----------------
__device__ __forceinline__ u64 hshift3_and(u64 c, u64 l, u64 r){
  return c & ((c << 1) | (l >> 63)) & ((c >> 1) | (r << 63));
}
__device__ __forceinline__ u64 hshift3_or(u64 c, u64 l, u64 r){
  return c | (c << 1) | (l >> 63) | (c >> 1) | (r << 63);
}
__device__ __forceinline__ u64 hshift5_and(u64 c, u64 l, u64 r){
  return hshift3_and(c, l, r) & ((c << 2) | (l >> 62)) & ((c >> 2) | (r << 62));
}
__device__ __forceinline__ u64 hshift5_or(u64 c, u64 l, u64 r){
  return hshift3_or(c, l, r) | (c << 2) | (l >> 62) | (c >> 2) | (r << 62);
}

// load word (row, wi) with image-vertical zero pad
__device__ __forceinline__ u64 ldw(const u64* __restrict__ in, int img, int rowInImg, int wi){
  if ((unsigned)rowInImg >= (unsigned)HH) return 0ULL;
  if ((unsigned)wi >= (unsigned)WPR) return 0ULL;
  return in[((size_t)img*HH + rowInImg)*WPR + wi];
}

// ---------------- LDS union-find (slab-local, path halving) ---------------
__device__ __forceinline__ int lfind(int* lp, int p){
  while (true){
    int q = lp[p];
    int g = lp[q];
    if (q == g) return q;
    atomicMin(&lp[p], g);
    p = g;
  }
}
__device__ __forceinline__ void lunion(int* lp, int a, int b){
  while (true){
    a = lfind(lp, a);
    b = lfind(lp, b);
    if (a == b) return;
    if (a < b){ int t = a; a = b; b = t; }
    int old = atomicMin(&lp[a], b);
    if (old == a) return;
    a = old;
  }
}

// ---------------- open (erode3+dilate3) + runs + SLAB-LOCAL union-find ----
#define ORPB 32
__global__ __launch_bounds__(256)
void k_openlocal(const u64* __restrict__ bits, uint32_t* __restrict__ runs,
                 int* __restrict__ cnt, int* __restrict__ parent,
                 int* __restrict__ area, int* __restrict__ clabel){
  __shared__ u64 er[ORPB + 2][WPR];
  __shared__ u64 dl[ORPB][WPR];
  __shared__ uint32_t lruns[ORPB][RS];
  __shared__ int lcnt[ORPB];
  __shared__ int lparent[ORPB*RS];     // 4096 entries
  int R0 = blockIdx.x * ORPB;
  int img = R0 >> 9;
  int y0 = R0 & (HH - 1);

  // phase E: erode3x3 rows y0-1 .. y0+32 (reads bitmap from L2)
  for (int s = threadIdx.x; s < (ORPB + 2)*WPR; s += 256){
    int j = s >> 3;                           // er row; image row y0-1+j
    int wi = s & 7;
    int yy = y0 - 1 + j;
    u64 acc = ~0ULL;
    #pragma unroll
    for (int dy = -1; dy <= 1; ++dy){
      int y = yy + dy;
      u64 c = ldw(bits, img, y, wi);
      u64 l = ldw(bits, img, y, wi - 1);
      u64 r = ldw(bits, img, y, wi + 1);
      acc &= ((unsigned)y < (unsigned)HH) ? hshift3_and(c, l, r) : 0ULL;
    }
    if ((unsigned)yy >= (unsigned)HH) acc = 0ULL;
    er[j][wi] = acc;
  }
  __syncthreads();

  // phase D: dilate3x3 -> dl
  for (int s = threadIdx.x; s < ORPB*WPR; s += 256){
    int ri = s >> 3;
    int wi = s & 7;
    u64 acc = 0ULL;
    #pragma unroll
    for (int dy = 0; dy < 3; ++dy){
      int li = ri + dy;
      u64 c = er[li][wi];
      u64 l = (wi > 0) ? er[li][wi-1] : 0ULL;
      u64 r = (wi < 7) ? er[li][wi+1] : 0ULL;
      acc |= hshift3_or(c, l, r);
    }
    dl[ri][wi] = acc;
  }
  __syncthreads();

  // init local parent (identity)
  for (int i = threadIdx.x; i < ORPB*RS; i += 256) lparent[i] = i;

  // phase R: run extraction, one thread per row (writes global + LDS copies)
  if (threadIdx.x < ORPB){
    int ri = threadIdx.x;
    int r = R0 + ri;
    u64 w[8];
    #pragma unroll
    for (int i = 0; i < 8; ++i) w[i] = dl[ri][i];
    int base = r*RS;
    int k = 0;
    int pending = -1;
    u64 carry = 0;
    #pragma unroll
    for (int wi = 0; wi < 8; ++wi){
      u64 b = w[wi];
      u64 nb0 = (wi < 7) ? (w[wi+1] & 1ULL) : 0ULL;
      u64 starts = b & ~((b << 1) | carry);
      u64 ends   = b & ~(b >> 1);
      if (nb0) ends &= ~(1ULL << 63);
      carry = b >> 63;
      while (ends){
        int e = __ffsll((long long)ends) - 1; ends &= ends - 1;
        int s;
        if (pending >= 0){ s = pending; pending = -1; }
        else { s = wi*64 + (__ffsll((long long)starts) - 1); starts &= starts - 1; }
        uint32_t rv = (uint32_t)s | ((uint32_t)(wi*64 + e) << 16);
        int id = base + k;
        runs[id] = rv; lruns[ri][k] = rv;
        area[id] = 0; clabel[id] = 0;
        k++;
      }
      if (starts) pending = wi*64 + (__ffsll((long long)starts) - 1);
    }
    cnt[r] = k; lcnt[ri] = k;
  }
  __syncthreads();

  // phase L: local link rows 1..31 (8 threads per row = 256 threads exactly)
  {
    int ri = threadIdx.x >> 3;
    int k0 = threadIdx.x & 7;
    if (ri > 0){
      int ca = lcnt[ri], cb = lcnt[ri-1];
      if (cb > 0){
        for (int k = k0; k < ca; k += 8){
          uint32_t ra = lruns[ri][k]; int sA = (int)(ra & 0xffff), eA = (int)(ra >> 16);
          int lo = 0, hi = cb, target = sA - 1;
          while (lo < hi){
            int mid = (lo + hi) >> 1;
            if ((int)(lruns[ri-1][mid] >> 16) < target) lo = mid + 1; else hi = mid;
          }
          for (int j = lo; j < cb; ++j){
            if ((int)(lruns[ri-1][j] & 0xffff) > eA + 1) break;
            lunion(lparent, ri*RS + k, (ri-1)*RS + j);
          }
        }
      }
    }
  }
  __syncthreads();

  // phase W: write global parent = slab root (global id space)
  {
    int ri = threadIdx.x >> 3;
    int k0 = threadIdx.x & 7;
    int n = lcnt[ri];
    for (int k = k0; k < n; k += 8){
      int lid = ri*RS + k;
      parent[R0*RS + lid] = R0*RS + lfind(lparent, lid);
    }
  }
}

// ---------------- global union-find (path halving) ----------------
__device__ __forceinline__ int uf_find(int* parent, int p){
  while (true){
    int q = parent[p];
    int g = parent[q];
    if (q == g) return q;
    atomicMin(&parent[p], g);
    p = g;
  }
}
__device__ __forceinline__ void uf_union(int* parent, int a, int b){
  while (true){
    a = uf_find(parent, a);
    b = uf_find(parent, b);
    if (a == b) return;
    if (a < b){ int t = a; a = b; b = t; }
    int old = atomicMin(&parent[a], b);
    if (old == a) return;
    a = old;
  }
}

// ---------------- boundary link: only rows at slab seams ------------------
#define NBND (HH/ORPB - 1)
__global__ void k_linkb(const uint32_t* __restrict__ runs, const int* __restrict__ cnt,
                        int* __restrict__ parent){
  int t = blockIdx.x*blockDim.x + threadIdx.x;
  int bi = t >> 3, k0 = t & 7;
  if (bi >= BB*NBND) return;
  int img = bi / NBND, j = bi % NBND;
  int r = img*HH + (j + 1)*ORPB;              // top row of slab; link to r-1
  int ca = cnt[r];
  int cb = cnt[r-1];
  if (cb == 0) return;
  const uint32_t* RB = runs + (size_t)(r-1)*RS;
  for (int k = k0; k < ca; k += 8){
    int id = r*RS + k;
    uint32_t ra = runs[id]; int sA = (int)(ra & 0xffff), eA = (int)(ra >> 16);
    int lo = 0, hi = cb, target = sA - 1;
    while (lo < hi){
      int mid = (lo + hi) >> 1;
      if ((int)(RB[mid] >> 16) < target) lo = mid + 1; else hi = mid;
    }
    for (int jj = lo; jj < cb; ++jj){
      uint32_t rb = RB[jj];
      if ((int)(rb & 0xffff) > eA + 1) break;
      uf_union(parent, id, (r-1)*RS + jj);
    }
  }
}

// ---------------- flatten: read-only find + LDS-hash block aggregation ----
// EXACT round-9 body (no embedded compaction — round-10's in-loop divergent
// global atomic caused a 40x codegen/serialization pathology).
#define FHASH 1024
__global__ __launch_bounds__(256)
void k_flatten(const uint32_t* __restrict__ runs, const int* __restrict__ cnt,
               int* __restrict__ parent, int* __restrict__ area,
               int* __restrict__ clabel){
  __shared__ int hKey[FHASH];
  __shared__ int hSum[FHASH];
  __shared__ int hMax[FHASH];
  for (int i = threadIdx.x; i < FHASH; i += 256){ hKey[i] = -1; hSum[i] = 0; hMax[i] = 0; }
  __syncthreads();
  int t = blockIdx.x*blockDim.x + threadIdx.x;
  int r = t / KPR, k0 = t % KPR;
  int n = cnt[r];
  int y = r & (HH - 1);
  for (int k = k0; k < n; k += KPR){
    int id = r*RS + k;
    int p = parent[id];
    while (true){ int q = parent[p]; if (q == p) break; p = q; }   // read-only find
    parent[id] = p;                     // final flatten (true root; forest static)
    uint32_t run = runs[id]; int s = (int)(run & 0xffff), e = (int)(run >> 16);
    int len = e - s + 1, lab = y*WW + e + 1;
    unsigned h = ((unsigned)p * 2654435761u) & (FHASH - 1);
    while (true){
      int cur = hKey[h];
      if (cur == p) break;
      if (cur == -1){
        int old = atomicCAS(&hKey[h], -1, p);
        if (old == -1 || old == p) break;
      }
      h = (h + 1) & (FHASH - 1);
    }
    atomicAdd(&hSum[h], len);
    atomicMax(&hMax[h], lab);
  }
  __syncthreads();
  for (int i = threadIdx.x; i < FHASH; i += 256){
    int key = hKey[i];
    if (key >= 0){
      atomicAdd(&area[key], hSum[i]);
      atomicMax(&clabel[key], hMax[i]);
    }
  }
}

// ---------------- compact roots per image (separate pass, round-7 style) --
__global__ void k_roots(const int* __restrict__ cnt, const int* __restrict__ parent,
                        const int* __restrict__ area, const int* __restrict__ clabel,
                        int* __restrict__ rootcnt, int* __restrict__ rootA,
                        int* __restrict__ rootL){
  int t = blockIdx.x*blockDim.x + threadIdx.x;
  if (t >= NROWS*KPR) return;
  int r = t / KPR, k0 = t % KPR;
  int n = cnt[r];
  int b = r >> 9;
  for (int k = k0; k < n; k += KPR){
    int id = r*RS + k;
    if (parent[id] != id) continue;          // roots only
    int a = area[id];
    if (a < 200) continue;                   // MIN_AREA -> <=1310 per image
    int idx = atomicAdd(&rootcnt[b], 1);
    rootA[b*MAXROOTS + idx] = a;
    rootL[b*MAXROOTS + idx] = clabel[id];
  }
}

// ---------------- top-2 per image (area desc, label asc tie) --------------
__device__ __forceinline__ void ins2(int v, int i, int& v1, int& i1, int& v2, int& i2){
  if (v > v1 || (v == v1 && i < i1)) { v2 = v1; i2 = i1; v1 = v; i1 = i; }
  else if (v > v2 || (v == v2 && i < i2)) { v2 = v; i2 = i; }
}

__global__ void k_top2(const int* __restrict__ rootcnt, const int* __restrict__ rootA,
                       const int* __restrict__ rootL, int* __restrict__ keepL){
  __shared__ int sv1[64], si1[64], sv2[64], si2[64];
  int b = blockIdx.x;
  int n = rootcnt[b];
  int v1 = 0, i1 = INT_MAX, v2 = 0, i2 = INT_MAX;
  for (int k = threadIdx.x; k < n; k += 64)
    ins2(rootA[b*MAXROOTS + k], rootL[b*MAXROOTS + k], v1, i1, v2, i2);
  int t = threadIdx.x;
  sv1[t] = v1; si1[t] = i1; sv2[t] = v2; si2[t] = i2;
  __syncthreads();
  for (int s = 32; s > 0; s >>= 1){
    if (t < s){
      int a1 = sv1[t], b1 = si1[t], a2 = sv2[t], b2 = si2[t];
      ins2(sv1[t+s], si1[t+s], a1, b1, a2, b2);
      ins2(sv2[t+s], si2[t+s], a1, b1, a2, b2);
      sv1[t] = a1; si1[t] = b1; sv2[t] = a2; si2[t] = b2;
    }
    __syncthreads();
  }
  if (t == 0){
    keepL[b*2 + 0] = (sv1[0] > 0) ? si1[0] : 0;   // 0 invalid (labels >= 1)
    keepL[b*2 + 1] = (sv2[0] > 0) ? si2[0] : 0;
  }
}

// ---------------- fused keep-build + close (dilate5+erode5) + expand ------
__device__ __forceinline__ u64 rmask(int s, int e){  // bits s..e inclusive
  u64 hi = (e >= 63) ? ~0ULL : ((1ULL << (e + 1)) - 1);
  u64 lo = (1ULL << s) - 1;
  return hi & ~lo;
}

#define CRPB 32
__global__ __launch_bounds__(256)
void k_closeexpand(const uint32_t* __restrict__ runs, const int* __restrict__ cnt,
                   const int* __restrict__ parent, const int* __restrict__ clabel,
                   const int* __restrict__ keepL, float* __restrict__ out){
  __shared__ u64 kp[CRPB + 8][WPR];   // keep rows y0-4 .. y0+35
  __shared__ u64 dil[CRPB + 4][WPR];  // dilated rows y0-2 .. y0+33
  __shared__ u64 ero[CRPB][WPR];
  int R0 = blockIdx.x * CRPB;
  int img = R0 >> 9;
  int y0 = R0 & (HH - 1);
  int L1 = keepL[img*2], L2 = keepL[img*2 + 1];
  // phase 0: build keep bit rows from kept runs (thread per row, 40 rows)
  for (int s = threadIdx.x; s < CRPB + 8; s += 256){
    int y = y0 + s - 4;
    u64 wb[8] = {0,0,0,0,0,0,0,0};
    if ((unsigned)y < (unsigned)HH){
      int row = img*HH + y;
      int n = cnt[row];
      for (int k = 0; k < n; ++k){
        int id = row*RS + k;
        int L = clabel[parent[id]];           // parent flattened -> 1 hop
        if (L != L1 && L != L2) continue;
        uint32_t run = runs[id]; int st = (int)(run & 0xffff), e = (int)(run >> 16);
        int w0 = st >> 6, w1 = e >> 6;
        if (w0 == w1) wb[w0] |= rmask(st & 63, e & 63);
        else {
          wb[w0] |= rmask(st & 63, 63);
          for (int wi = w0 + 1; wi < w1; ++wi) wb[wi] = ~0ULL;
          wb[w1] |= rmask(0, e & 63);
        }
      }
    }
    #pragma unroll
    for (int wi = 0; wi < 8; ++wi) kp[s][wi] = wb[wi];
  }
  __syncthreads();
  // phase 1: dilate5 rows y0-2 .. y0+33
  for (int s = threadIdx.x; s < (CRPB + 4)*WPR; s += 256){
    int li = s >> 3;                           // kp index li+2 is center
    int wi = s & 7;
    u64 acc = 0ULL;
    #pragma unroll
    for (int dy = -2; dy <= 2; ++dy){
      int ki = li + 2 + dy;                    // 0..39
      u64 c = kp[ki][wi];
      u64 l = (wi > 0) ? kp[ki][wi-1] : 0ULL;
      u64 r = (wi < 7) ? kp[ki][wi+1] : 0ULL;
      acc |= hshift5_or(c, l, r);
    }
    dil[li][wi] = acc;
  }
  __syncthreads();
  // phase 2: erode5 center rows (zero pad outside image)
  for (int s = threadIdx.x; s < CRPB*WPR; s += 256){
    int ri = s >> 3;
    int wi = s & 7;
    int y = y0 + ri;
    u64 acc = ~0ULL;
    #pragma unroll
    for (int dy = -2; dy <= 2; ++dy){
      int yy = y + dy;
      u64 h;
      if ((unsigned)yy >= (unsigned)HH) h = 0ULL;
      else {
        int li = ri + 2 + dy;
        u64 c = dil[li][wi];
        u64 l = (wi > 0) ? dil[li][wi-1] : 0ULL;
        u64 r = (wi < 7) ? dil[li][wi+1] : 0ULL;
        h = hshift5_and(c, l, r);
      }
      acc &= h;
    }
    ero[ri][wi] = acc;
  }
  __syncthreads();
  // phase 3: expand to f32, coalesced float4 stores
  float4* O = reinterpret_cast<float4*>(out + (size_t)R0*WW);
  for (int i = threadIdx.x; i < CRPB*WW/4; i += 256){
    int px = i * 4;
    int row = px >> 9;
    int x = px & (WW - 1);
    u64 word = ero[row][x >> 6];
    unsigned nib = (unsigned)((word >> (x & 63)) & 0xFULL);
    float4 f;
    f.x = (float)( nib       & 1);
    f.y = (float)((nib >> 1) & 1);
    f.z = (float)((nib >> 2) & 1);
    f.w = (float)((nib >> 3) & 1);
    O[i] = f;
  }
}

// ---------------- launch ----------------
extern "C" void kernel_launch(void* const* d_in, const int* in_sizes, int n_in,
                              void* d_out, int out_size, void* d_ws, size_t ws_size,
                              hipStream_t stream){
  const float* x = (const float*)d_in[0];
  float* out = (float*)d_out;
  char* ws = (char*)d_ws;

  const size_t BITS_OFF    = 0;                         // 2 MiB (thresh bitmap)
  const size_t RUNS_OFF    = BITS_OFF   + 2097152ull;   // 16 MiB
  const size_t PAR_OFF     = RUNS_OFF   + (size_t)MAXRUNS*4;
  const size_t AREA_OFF    = PAR_OFF    + (size_t)MAXRUNS*4;
  const size_t CLAB_OFF    = AREA_OFF   + (size_t)MAXRUNS*4;
  const size_t CNT_OFF     = CLAB_OFF   + (size_t)MAXRUNS*4;
  const size_t RCNT_OFF    = CNT_OFF    + (size_t)NROWS*4;
  const size_t RA_OFF      = RCNT_OFF   + 1024ull;
  const size_t RL_OFF      = RA_OFF     + (size_t)BB*MAXROOTS*4;
  const size_t KEEPL_OFF   = RL_OFF     + (size_t)BB*MAXROOTS*4;

  u64*      bits     = (u64*)(ws + BITS_OFF);
  uint32_t* runs     = (uint32_t*)(ws + RUNS_OFF);
  int*      parent   = (int*)(ws + PAR_OFF);
  int*      area     = (int*)(ws + AREA_OFF);
  int*      clabel   = (int*)(ws + CLAB_OFF);
  int*      cnt      = (int*)(ws + CNT_OFF);
  int*      rootcnt  = (int*)(ws + RCNT_OFF);
  int*      rootA    = (int*)(ws + RA_OFF);
  int*      rootL    = (int*)(ws + RL_OFF);
  int*      keepL    = (int*)(ws + KEEPL_OFF);

  const int T = 256;
  dim3 blk(T);

  // 1) threshold+pack (full occupancy stream read; zeroes rootcnt)
  k_threshpack<<<dim3(NPIX/16/T), blk, 0, stream>>>(x, bits, rootcnt);
  // 2) open + runs + slab-local union-find (LDS)
  k_openlocal<<<dim3(NROWS/ORPB), blk, 0, stream>>>(bits, runs, cnt, parent, area, clabel);
  // 3) boundary link (960 rows only)
  k_linkb<<<dim3((BB*NBND*8 + T - 1)/T), blk, 0, stream>>>(runs, cnt, parent);
  // 4) flatten + block-hash accumulate (round-9 exact)
  k_flatten<<<dim3(NROWS*KPR/T), blk, 0, stream>>>(runs, cnt, parent, area, clabel);
  // 5) compact roots (separate pass)
  k_roots<<<dim3(NROWS*KPR/T), blk, 0, stream>>>(cnt, parent, area, clabel,
                                                 rootcnt, rootA, rootL);
  // 6) top-2 per image over compacted candidates
  k_top2<<<dim3(BB), dim3(64), 0, stream>>>(rootcnt, rootA, rootL, keepL);
  // 7) fused keep-build + close + expand -> f32 out
  k_closeexpand<<<dim3(NROWS/CRPB), blk, 0, stream>>>(runs, cnt, parent, clabel, keepL, out);

  (void)in_sizes; (void)n_in; (void)out_size; (void)ws_size;
}

// Round 13
// 115.636 us; speedup vs baseline: 14.6879x; 1.0363x over previous
//
#include <hip/hip_runtime.h>
#include <stdint.h>
#include <limits.h>

#define BB 64
#define HH 512
#define WW 512
#define WPR 8                  // 64-bit words per row
#define HWP (HH*WW)            // 262144
#define NPIX (BB*HWP)          // 16777216
#define NROWS (BB*HH)          // 32768
#define RS 128                 // exact max runs/row in opened mask (len>=3, gap>=1)
#define MAXRUNS (NROWS*RS)     // 4194304
#define KPR 32                 // flatten/roots threads per row (hash capacity bound)
#define MAXROOTS 2048          // area>=200 roots per image <= 262144/200 = 1310

typedef unsigned char u8;
typedef unsigned long long u64;

__device__ __forceinline__ int imax(int a, int b){ return a > b ? a : b; }

// ---------------- helpers for bit morphology ----------------
__device__ __forceinline__ u64 hshift3_and(u64 c, u64 l, u64 r){
  return c & ((c << 1) | (l >> 63)) & ((c >> 1) | (r << 63));
}
__device__ __forceinline__ u64 hshift3_or(u64 c, u64 l, u64 r){
  return c | (c << 1) | (l >> 63) | (c >> 1) | (r << 63);
}
__device__ __forceinline__ u64 hshift5_and(u64 c, u64 l, u64 r){
  return hshift3_and(c, l, r) & ((c << 2) | (l >> 62)) & ((c >> 2) | (r << 62));
}
__device__ __forceinline__ u64 hshift5_or(u64 c, u64 l, u64 r){
  return hshift3_or(c, l, r) | (c << 2) | (l >> 62) | (c >> 2) | (r << 62);
}

// ---------------- LDS union-find (slab-local, path halving) ---------------
__device__ __forceinline__ int lfind(int* lp, int p){
  while (true){
    int q = lp[p];
    int g = lp[q];
    if (q == g) return q;
    atomicMin(&lp[p], g);
    p = g;
  }
}
__device__ __forceinline__ void lunion(int* lp, int a, int b){
  while (true){
    a = lfind(lp, a);
    b = lfind(lp, b);
    if (a == b) return;
    if (a < b){ int t = a; a = b; b = t; }
    int old = atomicMin(&lp[a], b);
    if (old == a) return;
    a = old;
  }
}

// ------- fused threshold + open (erode3+dilate3) + runs + slab-local UF ---
// One block = 32-row slab (1024 blocks total -> 4 blocks/CU, 16 waves/CU
// during the streaming read; round-8's fusion failed at 512 blocks/8 waves).
// Thresholds 36 rows (12.5% halo re-read) into LDS via ballot-pack; the
// bitmap never touches global memory.
#define ORPB 32
__global__ __launch_bounds__(256)
void k_thropen(const float* __restrict__ x, uint32_t* __restrict__ runs,
               int* __restrict__ cnt, int* __restrict__ parent,
               int* __restrict__ area, int* __restrict__ clabel,
               int* __restrict__ rootcnt){
  __shared__ u64 thr[ORPB + 4][WPR];   // image rows y0-2 .. y0+33
  __shared__ u64 er[ORPB + 2][WPR];    // y0-1 .. y0+32
  __shared__ u64 dl[ORPB][WPR];        // y0   .. y0+31
  __shared__ uint32_t lruns[ORPB][RS];
  __shared__ int lcnt[ORPB];
  __shared__ int lparent[ORPB*RS];     // 4096 entries
  int R0 = blockIdx.x * ORPB;
  int img = R0 >> 9;
  int y0 = R0 & (HH - 1);
  int wid  = threadIdx.x >> 6;
  int lane = threadIdx.x & 63;
  if (blockIdx.x == 0 && threadIdx.x < BB) rootcnt[threadIdx.x] = 0;

  // phase T: threshold 36 rows, 2 rows per wave-iteration (ballot-pack)
  for (int pair = wid; pair < (ORPB + 4)/2; pair += 4){
    int lrow = 2*pair + (lane >> 5);          // LDS row 0..35
    int y = y0 - 2 + lrow;                    // image row
    unsigned m = 0;
    if ((unsigned)y < (unsigned)HH){
      int xpx = (lane & 31) * 16;
      const float4* X = reinterpret_cast<const float4*>(
          x + ((size_t)img*HH + y)*WW + xpx);
      #pragma unroll
      for (int q = 0; q < 4; ++q){
        float4 v = X[q];
        m |= (unsigned)(v.x > -0.5f) << (q*4 + 0);
        m |= (unsigned)(v.y > -0.5f) << (q*4 + 1);
        m |= (unsigned)(v.z > -0.5f) << (q*4 + 2);
        m |= (unsigned)(v.w > -0.5f) << (q*4 + 3);
      }
    }
    int sub = lane & 3;
    unsigned p1 = __shfl_xor(m, 1);
    unsigned v32 = (sub & 1) ? (p1 | (m << 16)) : (m | (p1 << 16));
    unsigned p2 = __shfl_xor(v32, 2);
    if (sub == 0)
      thr[lrow][(lane >> 2) & 7] = (u64)v32 | ((u64)p2 << 32);
  }
  __syncthreads();

  // phase E: erode3x3 -> er rows j (image row y0-1+j), thr zero-pad at borders
  for (int s = threadIdx.x; s < (ORPB + 2)*WPR; s += 256){
    int j = s >> 3;
    int wi = s & 7;
    int rr = y0 - 1 + j;                      // image row of er[j]
    u64 acc = ~0ULL;
    #pragma unroll
    for (int dy = 0; dy < 3; ++dy){
      int ti = j + dy;                        // thr rows j..j+2 (center j+1)
      u64 c = thr[ti][wi];
      u64 l = (wi > 0) ? thr[ti][wi-1] : 0ULL;
      u64 r = (wi < 7) ? thr[ti][wi+1] : 0ULL;
      acc &= hshift3_and(c, l, r);
    }
    if ((unsigned)rr >= (unsigned)HH) acc = 0ULL;
    er[j][wi] = acc;
  }
  __syncthreads();

  // phase D: dilate3x3 -> dl
  for (int s = threadIdx.x; s < ORPB*WPR; s += 256){
    int ri = s >> 3;
    int wi = s & 7;
    u64 acc = 0ULL;
    #pragma unroll
    for (int dy = 0; dy < 3; ++dy){
      int li = ri + dy;                       // er rows ri..ri+2 (center ri+1)
      u64 c = er[li][wi];
      u64 l = (wi > 0) ? er[li][wi-1] : 0ULL;
      u64 r = (wi < 7) ? er[li][wi+1] : 0ULL;
      acc |= hshift3_or(c, l, r);
    }
    dl[ri][wi] = acc;
  }
  __syncthreads();

  // init local parent (identity)
  for (int i = threadIdx.x; i < ORPB*RS; i += 256) lparent[i] = i;

  // phase R: run extraction, one thread per row (writes global + LDS copies)
  if (threadIdx.x < ORPB){
    int ri = threadIdx.x;
    int r = R0 + ri;
    u64 w[8];
    #pragma unroll
    for (int i = 0; i < 8; ++i) w[i] = dl[ri][i];
    int base = r*RS;
    int k = 0;
    int pending = -1;
    u64 carry = 0;
    #pragma unroll
    for (int wi = 0; wi < 8; ++wi){
      u64 b = w[wi];
      u64 nb0 = (wi < 7) ? (w[wi+1] & 1ULL) : 0ULL;
      u64 starts = b & ~((b << 1) | carry);
      u64 ends   = b & ~(b >> 1);
      if (nb0) ends &= ~(1ULL << 63);
      carry = b >> 63;
      while (ends){
        int e = __ffsll((long long)ends) - 1; ends &= ends - 1;
        int s;
        if (pending >= 0){ s = pending; pending = -1; }
        else { s = wi*64 + (__ffsll((long long)starts) - 1); starts &= starts - 1; }
        uint32_t rv = (uint32_t)s | ((uint32_t)(wi*64 + e) << 16);
        int id = base + k;
        runs[id] = rv; lruns[ri][k] = rv;
        area[id] = 0; clabel[id] = 0;
        k++;
      }
      if (starts) pending = wi*64 + (__ffsll((long long)starts) - 1);
    }
    cnt[r] = k; lcnt[ri] = k;
  }
  __syncthreads();

  // phase L: local link rows 1..31 (8 threads per row = 256 threads exactly)
  {
    int ri = threadIdx.x >> 3;
    int k0 = threadIdx.x & 7;
    if (ri > 0){
      int ca = lcnt[ri], cb = lcnt[ri-1];
      if (cb > 0){
        for (int k = k0; k < ca; k += 8){
          uint32_t ra = lruns[ri][k]; int sA = (int)(ra & 0xffff), eA = (int)(ra >> 16);
          int lo = 0, hi = cb, target = sA - 1;
          while (lo < hi){
            int mid = (lo + hi) >> 1;
            if ((int)(lruns[ri-1][mid] >> 16) < target) lo = mid + 1; else hi = mid;
          }
          for (int j = lo; j < cb; ++j){
            if ((int)(lruns[ri-1][j] & 0xffff) > eA + 1) break;
            lunion(lparent, ri*RS + k, (ri-1)*RS + j);
          }
        }
      }
    }
  }
  __syncthreads();

  // phase W: write global parent = slab root (global id space)
  {
    int ri = threadIdx.x >> 3;
    int k0 = threadIdx.x & 7;
    int n = lcnt[ri];
    for (int k = k0; k < n; k += 8){
      int lid = ri*RS + k;
      parent[R0*RS + lid] = R0*RS + lfind(lparent, lid);
    }
  }
}

// ---------------- global union-find (path halving) ----------------
__device__ __forceinline__ int uf_find(int* parent, int p){
  while (true){
    int q = parent[p];
    int g = parent[q];
    if (q == g) return q;
    atomicMin(&parent[p], g);
    p = g;
  }
}
__device__ __forceinline__ void uf_union(int* parent, int a, int b){
  while (true){
    a = uf_find(parent, a);
    b = uf_find(parent, b);
    if (a == b) return;
    if (a < b){ int t = a; a = b; b = t; }
    int old = atomicMin(&parent[a], b);
    if (old == a) return;
    a = old;
  }
}

// ---------------- boundary link: only rows at slab seams ------------------
#define NBND (HH/ORPB - 1)
__global__ void k_linkb(const uint32_t* __restrict__ runs, const int* __restrict__ cnt,
                        int* __restrict__ parent){
  int t = blockIdx.x*blockDim.x + threadIdx.x;
  int bi = t >> 3, k0 = t & 7;
  if (bi >= BB*NBND) return;
  int img = bi / NBND, j = bi % NBND;
  int r = img*HH + (j + 1)*ORPB;              // top row of slab; link to r-1
  int ca = cnt[r];
  int cb = cnt[r-1];
  if (cb == 0) return;
  const uint32_t* RB = runs + (size_t)(r-1)*RS;
  for (int k = k0; k < ca; k += 8){
    int id = r*RS + k;
    uint32_t ra = runs[id]; int sA = (int)(ra & 0xffff), eA = (int)(ra >> 16);
    int lo = 0, hi = cb, target = sA - 1;
    while (lo < hi){
      int mid = (lo + hi) >> 1;
      if ((int)(RB[mid] >> 16) < target) lo = mid + 1; else hi = mid;
    }
    for (int jj = lo; jj < cb; ++jj){
      uint32_t rb = RB[jj];
      if ((int)(rb & 0xffff) > eA + 1) break;
      uf_union(parent, id, (r-1)*RS + jj);
    }
  }
}

// ---------------- flatten: read-only find + LDS-hash block aggregation ----
// Round-9/11 exact body (no embedded compaction — round-10 pathology).
#define FHASH 1024
__global__ __launch_bounds__(256)
void k_flatten(const uint32_t* __restrict__ runs, const int* __restrict__ cnt,
               int* __restrict__ parent, int* __restrict__ area,
               int* __restrict__ clabel){
  __shared__ int hKey[FHASH];
  __shared__ int hSum[FHASH];
  __shared__ int hMax[FHASH];
  for (int i = threadIdx.x; i < FHASH; i += 256){ hKey[i] = -1; hSum[i] = 0; hMax[i] = 0; }
  __syncthreads();
  int t = blockIdx.x*blockDim.x + threadIdx.x;
  int r = t / KPR, k0 = t % KPR;
  int n = cnt[r];
  int y = r & (HH - 1);
  for (int k = k0; k < n; k += KPR){
    int id = r*RS + k;
    int p = parent[id];
    while (true){ int q = parent[p]; if (q == p) break; p = q; }   // read-only find
    parent[id] = p;                     // final flatten (true root; forest static)
    uint32_t run = runs[id]; int s = (int)(run & 0xffff), e = (int)(run >> 16);
    int len = e - s + 1, lab = y*WW + e + 1;
    unsigned h = ((unsigned)p * 2654435761u) & (FHASH - 1);
    while (true){
      int cur = hKey[h];
      if (cur == p) break;
      if (cur == -1){
        int old = atomicCAS(&hKey[h], -1, p);
        if (old == -1 || old == p) break;
      }
      h = (h + 1) & (FHASH - 1);
    }
    atomicAdd(&hSum[h], len);
    atomicMax(&hMax[h], lab);
  }
  __syncthreads();
  for (int i = threadIdx.x; i < FHASH; i += 256){
    int key = hKey[i];
    if (key >= 0){
      atomicAdd(&area[key], hSum[i]);
      atomicMax(&clabel[key], hMax[i]);
    }
  }
}

// ---------------- compact roots per image (separate pass) ----------------
__global__ void k_roots(const int* __restrict__ cnt, const int* __restrict__ parent,
                        const int* __restrict__ area, const int* __restrict__ clabel,
                        int* __restrict__ rootcnt, int* __restrict__ rootA,
                        int* __restrict__ rootL){
  int t = blockIdx.x*blockDim.x + threadIdx.x;
  if (t >= NROWS*KPR) return;
  int r = t / KPR, k0 = t % KPR;
  int n = cnt[r];
  int b = r >> 9;
  for (int k = k0; k < n; k += KPR){
    int id = r*RS + k;
    if (parent[id] != id) continue;          // roots only
    int a = area[id];
    if (a < 200) continue;                   // MIN_AREA -> <=1310 per image
    int idx = atomicAdd(&rootcnt[b], 1);
    rootA[b*MAXROOTS + idx] = a;
    rootL[b*MAXROOTS + idx] = clabel[id];
  }
}

// ---------------- top-2 per image (area desc, label asc tie) --------------
__device__ __forceinline__ void ins2(int v, int i, int& v1, int& i1, int& v2, int& i2){
  if (v > v1 || (v == v1 && i < i1)) { v2 = v1; i2 = i1; v1 = v; i1 = i; }
  else if (v > v2 || (v == v2 && i < i2)) { v2 = v; i2 = i; }
}

__global__ void k_top2(const int* __restrict__ rootcnt, const int* __restrict__ rootA,
                       const int* __restrict__ rootL, int* __restrict__ keepL){
  __shared__ int sv1[64], si1[64], sv2[64], si2[64];
  int b = blockIdx.x;
  int n = rootcnt[b];
  int v1 = 0, i1 = INT_MAX, v2 = 0, i2 = INT_MAX;
  for (int k = threadIdx.x; k < n; k += 64)
    ins2(rootA[b*MAXROOTS + k], rootL[b*MAXROOTS + k], v1, i1, v2, i2);
  int t = threadIdx.x;
  sv1[t] = v1; si1[t] = i1; sv2[t] = v2; si2[t] = i2;
  __syncthreads();
  for (int s = 32; s > 0; s >>= 1){
    if (t < s){
      int a1 = sv1[t], b1 = si1[t], a2 = sv2[t], b2 = si2[t];
      ins2(sv1[t+s], si1[t+s], a1, b1, a2, b2);
      ins2(sv2[t+s], si2[t+s], a1, b1, a2, b2);
      sv1[t] = a1; si1[t] = b1; sv2[t] = a2; si2[t] = b2;
    }
    __syncthreads();
  }
  if (t == 0){
    keepL[b*2 + 0] = (sv1[0] > 0) ? si1[0] : 0;   // 0 invalid (labels >= 1)
    keepL[b*2 + 1] = (sv2[0] > 0) ? si2[0] : 0;
  }
}

// ---------------- fused keep-build + close (dilate5+erode5) + expand ------
__device__ __forceinline__ u64 rmask(int s, int e){  // bits s..e inclusive
  u64 hi = (e >= 63) ? ~0ULL : ((1ULL << (e + 1)) - 1);
  u64 lo = (1ULL << s) - 1;
  return hi & ~lo;
}

#define CRPB 32
__global__ __launch_bounds__(256)
void k_closeexpand(const uint32_t* __restrict__ runs, const int* __restrict__ cnt,
                   const int* __restrict__ parent, const int* __restrict__ clabel,
                   const int* __restrict__ keepL, float* __restrict__ out){
  __shared__ u64 kp[CRPB + 8][WPR];   // keep rows y0-4 .. y0+35
  __shared__ u64 dil[CRPB + 4][WPR];  // dilated rows y0-2 .. y0+33
  __shared__ u64 ero[CRPB][WPR];
  int R0 = blockIdx.x * CRPB;
  int img = R0 >> 9;
  int y0 = R0 & (HH - 1);
  int L1 = keepL[img*2], L2 = keepL[img*2 + 1];
  // phase 0: build keep bit rows from kept runs (thread per row, 40 rows)
  for (int s = threadIdx.x; s < CRPB + 8; s += 256){
    int y = y0 + s - 4;
    u64 wb[8] = {0,0,0,0,0,0,0,0};
    if ((unsigned)y < (unsigned)HH){
      int row = img*HH + y;
      int n = cnt[row];
      for (int k = 0; k < n; ++k){
        int id = row*RS + k;
        int L = clabel[parent[id]];           // parent flattened -> 1 hop
        if (L != L1 && L != L2) continue;
        uint32_t run = runs[id]; int st = (int)(run & 0xffff), e = (int)(run >> 16);
        int w0 = st >> 6, w1 = e >> 6;
        if (w0 == w1) wb[w0] |= rmask(st & 63, e & 63);
        else {
          wb[w0] |= rmask(st & 63, 63);
          for (int wi = w0 + 1; wi < w1; ++wi) wb[wi] = ~0ULL;
          wb[w1] |= rmask(0, e & 63);
        }
      }
    }
    #pragma unroll
    for (int wi = 0; wi < 8; ++wi) kp[s][wi] = wb[wi];
  }
  __syncthreads();
  // phase 1: dilate5 rows y0-2 .. y0+33
  for (int s = threadIdx.x; s < (CRPB + 4)*WPR; s += 256){
    int li = s >> 3;                           // kp index li+2 is center
    int wi = s & 7;
    u64 acc = 0ULL;
    #pragma unroll
    for (int dy = -2; dy <= 2; ++dy){
      int ki = li + 2 + dy;                    // 0..39
      u64 c = kp[ki][wi];
      u64 l = (wi > 0) ? kp[ki][wi-1] : 0ULL;
      u64 r = (wi < 7) ? kp[ki][wi+1] : 0ULL;
      acc |= hshift5_or(c, l, r);
    }
    dil[li][wi] = acc;
  }
  __syncthreads();
  // phase 2: erode5 center rows (zero pad outside image)
  for (int s = threadIdx.x; s < CRPB*WPR; s += 256){
    int ri = s >> 3;
    int wi = s & 7;
    int y = y0 + ri;
    u64 acc = ~0ULL;
    #pragma unroll
    for (int dy = -2; dy <= 2; ++dy){
      int yy = y + dy;
      u64 h;
      if ((unsigned)yy >= (unsigned)HH) h = 0ULL;
      else {
        int li = ri + 2 + dy;
        u64 c = dil[li][wi];
        u64 l = (wi > 0) ? dil[li][wi-1] : 0ULL;
        u64 r = (wi < 7) ? dil[li][wi+1] : 0ULL;
        h = hshift5_and(c, l, r);
      }
      acc &= h;
    }
    ero[ri][wi] = acc;
  }
  __syncthreads();
  // phase 3: expand to f32, coalesced float4 stores
  float4* O = reinterpret_cast<float4*>(out + (size_t)R0*WW);
  for (int i = threadIdx.x; i < CRPB*WW/4; i += 256){
    int px = i * 4;
    int row = px >> 9;
    int x = px & (WW - 1);
    u64 word = ero[row][x >> 6];
    unsigned nib = (unsigned)((word >> (x & 63)) & 0xFULL);
    float4 f;
    f.x = (float)( nib       & 1);
    f.y = (float)((nib >> 1) & 1);
    f.z = (float)((nib >> 2) & 1);
    f.w = (float)((nib >> 3) & 1);
    O[i] = f;
  }
}

// ---------------- launch ----------------
extern "C" void kernel_launch(void* const* d_in, const int* in_sizes, int n_in,
                              void* d_out, int out_size, void* d_ws, size_t ws_size,
                              hipStream_t stream){
  const float* x = (const float*)d_in[0];
  float* out = (float*)d_out;
  char* ws = (char*)d_ws;

  const size_t RUNS_OFF    = 0;                         // 16 MiB
  const size_t PAR_OFF     = RUNS_OFF   + (size_t)MAXRUNS*4;
  const size_t AREA_OFF    = PAR_OFF    + (size_t)MAXRUNS*4;
  const size_t CLAB_OFF    = AREA_OFF   + (size_t)MAXRUNS*4;
  const size_t CNT_OFF     = CLAB_OFF   + (size_t)MAXRUNS*4;
  const size_t RCNT_OFF    = CNT_OFF    + (size_t)NROWS*4;
  const size_t RA_OFF      = RCNT_OFF   + 1024ull;
  const size_t RL_OFF      = RA_OFF     + (size_t)BB*MAXROOTS*4;
  const size_t KEEPL_OFF   = RL_OFF     + (size_t)BB*MAXROOTS*4;

  uint32_t* runs     = (uint32_t*)(ws + RUNS_OFF);
  int*      parent   = (int*)(ws + PAR_OFF);
  int*      area     = (int*)(ws + AREA_OFF);
  int*      clabel   = (int*)(ws + CLAB_OFF);
  int*      cnt      = (int*)(ws + CNT_OFF);
  int*      rootcnt  = (int*)(ws + RCNT_OFF);
  int*      rootA    = (int*)(ws + RA_OFF);
  int*      rootL    = (int*)(ws + RL_OFF);
  int*      keepL    = (int*)(ws + KEEPL_OFF);

  const int T = 256;
  dim3 blk(T);

  // 1) fused threshold + open + runs + slab-local UF (zeroes rootcnt)
  k_thropen<<<dim3(NROWS/ORPB), blk, 0, stream>>>(x, runs, cnt, parent, area,
                                                  clabel, rootcnt);
  // 2) boundary link (960 rows only)
  k_linkb<<<dim3((BB*NBND*8 + T - 1)/T), blk, 0, stream>>>(runs, cnt, parent);
  // 3) flatten + block-hash accumulate
  k_flatten<<<dim3(NROWS*KPR/T), blk, 0, stream>>>(runs, cnt, parent, area, clabel);
  // 4) compact roots (separate pass)
  k_roots<<<dim3(NROWS*KPR/T), blk, 0, stream>>>(cnt, parent, area, clabel,
                                                 rootcnt, rootA, rootL);
  // 5) top-2 per image over compacted candidates
  k_top2<<<dim3(BB), dim3(64), 0, stream>>>(rootcnt, rootA, rootL, keepL);
  // 6) fused keep-build + close + expand -> f32 out
  k_closeexpand<<<dim3(NROWS/CRPB), blk, 0, stream>>>(runs, cnt, parent, clabel,
                                                      keepL, out);

  (void)in_sizes; (void)n_in; (void)out_size; (void)ws_size;
}